// Round 7
// baseline (8079.160 us; speedup 1.0000x reference)
//
#include <hip/hip_runtime.h>
#include <math.h>

// ---------- helpers ----------
__device__ __forceinline__ float lrelu(float v) { return v > 0.f ? v : 0.2f * v; }

__device__ __forceinline__ float wave_allred_sum(float v) {
#pragma unroll
    for (int off = 1; off < 64; off <<= 1) v += __shfl_xor(v, off, 64);
    return v;
}

// ---------- tiled f32 GEMM: C[M,Nc] = A[M,K] @ B[K,Nc] ----------
__global__ __launch_bounds__(256) void gemm_f32(const float* __restrict__ A,
                                                const float* __restrict__ B,
                                                float* __restrict__ C, int M, int K, int Nc) {
    __shared__ float As[16][64];
    __shared__ float Bs[16][64];
    int tid = threadIdx.x;
    int tx = tid & 15, ty = tid >> 4;
    int m0 = blockIdx.y * 64, n0 = blockIdx.x * 64;
    int lm = tid >> 2;       // 0..63 : row within A tile
    int lk = (tid & 3) * 4;  // 0,4,8,12
    int bk = tid >> 4;       // 0..15 : row within B tile
    int bn = (tid & 15) * 4;

    float acc[4][4] = {};
    for (int kt = 0; kt < K; kt += 16) {
        int gm = m0 + lm;
        float4 av = make_float4(0.f, 0.f, 0.f, 0.f);
        if (gm < M) av = *(const float4*)(A + (size_t)gm * K + kt + lk);
        As[lk + 0][lm] = av.x; As[lk + 1][lm] = av.y;
        As[lk + 2][lm] = av.z; As[lk + 3][lm] = av.w;
        *(float4*)&Bs[bk][bn] = *(const float4*)(B + (size_t)(kt + bk) * Nc + n0 + bn);
        __syncthreads();
#pragma unroll
        for (int k = 0; k < 16; k++) {
            float4 a = *(const float4*)&As[k][ty * 4];
            float4 b = *(const float4*)&Bs[k][tx * 4];
            acc[0][0] += a.x * b.x; acc[0][1] += a.x * b.y; acc[0][2] += a.x * b.z; acc[0][3] += a.x * b.w;
            acc[1][0] += a.y * b.x; acc[1][1] += a.y * b.y; acc[1][2] += a.y * b.z; acc[1][3] += a.y * b.w;
            acc[2][0] += a.z * b.x; acc[2][1] += a.z * b.y; acc[2][2] += a.z * b.z; acc[2][3] += a.z * b.w;
            acc[3][0] += a.w * b.x; acc[3][1] += a.w * b.y; acc[3][2] += a.w * b.z; acc[3][3] += a.w * b.w;
        }
        __syncthreads();
    }
#pragma unroll
    for (int i = 0; i < 4; i++) {
        int gm = m0 + ty * 4 + i;
        if (gm < M) {
            *(float4*)&C[(size_t)gm * Nc + n0 + tx * 4] =
                make_float4(acc[i][0], acc[i][1], acc[i][2], acc[i][3]);
        }
    }
}

// ---------- attention logits: one thread per (node, head) ----------
__global__ void attn_simple(const float* __restrict__ H, const float* __restrict__ asrc,
                            const float* __restrict__ adst, float* __restrict__ es,
                            float* __restrict__ ed, int N, int HC, int C) {
    int i = blockIdx.x * blockDim.x + threadIdx.x;
    if (i >= N * 4) return;
    int node = i >> 2, hh = i & 3;
    const float* hp = H + (size_t)node * HC + hh * C;
    const float* ap = asrc + hh * C;
    const float* bp = adst + hh * C;
    float e = 0.f, d = 0.f;
    for (int c = 0; c < C; c++) {
        float h = hp[c];
        e += h * ap[c];
        d += h * bp[c];
    }
    es[i] = e;
    ed[i] = d;
}

// ---------- softmax denominator: one thread per edge (incl. self-loops) ----------
__global__ void edge_denom(const int* __restrict__ src, const int* __restrict__ dst,
                           const float* __restrict__ es, const float* __restrict__ ed,
                           float* __restrict__ denom, int Etot, int E) {
    int eid = blockIdx.x * blockDim.x + threadIdx.x;
    if (eid >= Etot) return;
    int s = (eid < E) ? src[eid] : (eid - E);
    int d = (eid < E) ? dst[eid] : (eid - E);
#pragma unroll
    for (int h = 0; h < 4; h++) {
        float e = lrelu(es[s * 4 + h] + ed[d * 4 + h]);
        atomicAdd(&denom[d * 4 + h], expf(e));
    }
}

// ---------- aggregation: one wave per edge, atomic scatter into hagg[dst] ----------
template <int VPL>
__global__ __launch_bounds__(256) void agg_scatter(const float* __restrict__ H,
                                                   const float* __restrict__ es,
                                                   const float* __restrict__ ed,
                                                   const float* __restrict__ denom,
                                                   const int* __restrict__ src,
                                                   const int* __restrict__ dst,
                                                   float* __restrict__ hagg, int Etot, int E) {
    constexpr int HC = VPL * 64;
    int lane = threadIdx.x & 63;
    int eid = (blockIdx.x * blockDim.x + threadIdx.x) >> 6;
    if (eid >= Etot) return;
    int s = (eid < E) ? src[eid] : (eid - E);
    int d = (eid < E) ? dst[eid] : (eid - E);
    int hh = lane >> 4;
    float e = lrelu(es[s * 4 + hh] + ed[d * 4 + hh]);
    float alpha = expf(e) / denom[d * 4 + hh];
    const float* hp = H + (size_t)s * HC + lane * VPL;
    float* op = hagg + (size_t)d * HC + lane * VPL;
#pragma unroll
    for (int j = 0; j < VPL; j++) atomicAdd(&op[j], alpha * hp[j]);
}

// ---------- epilogue: bias + (ELU) + LayerNorm, one wave per node; f32 out ----------
template <int VPL>
__global__ __launch_bounds__(256) void epilogue(const float* __restrict__ hagg,
                                                const float* __restrict__ bias,
                                                const float* __restrict__ gamma,
                                                const float* __restrict__ beta,
                                                float* __restrict__ Xf, int N, int applyElu) {
    constexpr int HC = VPL * 64;
    int lane = threadIdx.x & 63;
    int node = (blockIdx.x * blockDim.x + threadIdx.x) >> 6;
    if (node >= N) return;
    float v[VPL];
    float s1 = 0.f, s2 = 0.f;
#pragma unroll
    for (int j = 0; j < VPL; j++) {
        int ch = lane * VPL + j;
        float t = hagg[(size_t)node * HC + ch] + bias[ch];
        if (applyElu) t = (t > 0.f) ? t : (expf(t) - 1.f);
        v[j] = t;
        s1 += t;
        s2 += t * t;
    }
    s1 = wave_allred_sum(s1);
    s2 = wave_allred_sum(s2);
    float mu = s1 / (float)HC;
    float var = s2 / (float)HC - mu * mu;
    float rs = rsqrtf(var + 1e-5f);
#pragma unroll
    for (int j = 0; j < VPL; j++) {
        int ch = lane * VPL + j;
        Xf[(size_t)node * HC + ch] = gamma[ch] * (v[j] - mu) * rs + beta[ch];
    }
}

// ---------- graph pooling (f32 node_emb from d_out, f32 graph_emb out) ----------
__global__ void gpool_kernel(const float* __restrict__ node_emb, const int* __restrict__ batch,
                             float* __restrict__ gsum, int* __restrict__ gcnt, int N) {
    int i = blockIdx.x * blockDim.x + threadIdx.x;
    if (i >= N * 128) return;
    int node = i >> 7, ch = i & 127;
    int g = batch[node];
    atomicAdd(&gsum[g * 128 + ch], node_emb[i]);
    if (ch == 0) atomicAdd(&gcnt[g], 1);
}

__global__ void gfinal_kernel(const float* __restrict__ gsum, const int* __restrict__ gcnt,
                              float* __restrict__ out, int Gn) {
    int i = blockIdx.x * blockDim.x + threadIdx.x;
    if (i >= Gn * 128) return;
    int g = i >> 7;
    out[i] = gsum[i] / fmaxf((float)gcnt[g], 1.f);
}

// ---------- launch ----------
extern "C" void kernel_launch(void* const* d_in, const int* in_sizes, int n_in, void* d_out,
                              int out_size, void* d_ws, size_t ws_size, hipStream_t stream) {
    const float* x = (const float*)d_in[0];
    const int* ei = (const int*)d_in[1];
    const int* batch = (const int*)d_in[2];
    const float* W1 = (const float*)d_in[3];
    const float* as1 = (const float*)d_in[4];
    const float* ad1 = (const float*)d_in[5];
    const float* b1 = (const float*)d_in[6];
    const float* g1 = (const float*)d_in[7];
    const float* be1 = (const float*)d_in[8];
    const float* W2 = (const float*)d_in[9];
    const float* as2 = (const float*)d_in[10];
    const float* ad2 = (const float*)d_in[11];
    const float* b2 = (const float*)d_in[12];
    const float* g2 = (const float*)d_in[13];
    const float* be2 = (const float*)d_in[14];
    const float* W3 = (const float*)d_in[15];
    const float* as3 = (const float*)d_in[16];
    const float* ad3 = (const float*)d_in[17];
    const float* b3 = (const float*)d_in[18];
    const float* g3 = (const float*)d_in[19];
    const float* be3 = (const float*)d_in[20];

    int N = in_sizes[2];
    int E = in_sizes[1] / 2;
    int Etot = E + N;

    char* w = (char*)d_ws;
    size_t off = 0;
    auto alloc = [&](size_t bytes) -> void* {
        void* p = w + off;
        off += (bytes + 255) & ~(size_t)255;
        return p;
    };
    float* gsum = (float*)alloc(64 * 128 * 4);   // |
    int* gcnt = (int*)alloc(64 * 4);             // | zero region (contiguous)
    size_t zbytes = off;
    float* denom = (float*)alloc((size_t)N * 16);  // zeroed per layer
    float* es = (float*)alloc((size_t)N * 16);
    float* ed = (float*)alloc((size_t)N * 16);
    float* Xbuf = (float*)alloc((size_t)N * 256 * 4);  // agg target + LN in-place + next GEMM in
    float* Hbuf = (float*)alloc((size_t)N * 256 * 4);  // GEMM out (h)
    // total ≈ 105 MB

    hipMemsetAsync(d_ws, 0, zbytes, stream);

    const int* srcrow = ei;      // edge_index[0]
    const int* dstrow = ei + E;  // edge_index[1]

    int mTiles = (N + 63) / 64;
    int nodeWaveBlocks = (N + 3) / 4;
    int edgeBlocks = (Etot + 255) / 256;
    int edgeWaveBlocks = (Etot + 3) / 4;
    int attnBlocks = (N * 4 + 255) / 256;

    float* out_node = (float*)d_out;                     // [N,128] f32
    float* out_graph = (float*)d_out + (size_t)N * 128;  // [64,128] f32

    // ---- layer 1: 768 -> 256 ----
    gemm_f32<<<dim3(4, mTiles), 256, 0, stream>>>(x, W1, Hbuf, N, 768, 256);
    attn_simple<<<attnBlocks, 256, 0, stream>>>(Hbuf, as1, ad1, es, ed, N, 256, 64);
    hipMemsetAsync(denom, 0, (size_t)N * 16, stream);
    edge_denom<<<edgeBlocks, 256, 0, stream>>>(srcrow, dstrow, es, ed, denom, Etot, E);
    hipMemsetAsync(Xbuf, 0, (size_t)N * 256 * 4, stream);
    agg_scatter<4><<<edgeWaveBlocks, 256, 0, stream>>>(Hbuf, es, ed, denom, srcrow, dstrow,
                                                       Xbuf, Etot, E);
    epilogue<4><<<nodeWaveBlocks, 256, 0, stream>>>(Xbuf, b1, g1, be1, Xbuf, N, 1);

    // ---- layer 2: 256 -> 256 ----
    gemm_f32<<<dim3(4, mTiles), 256, 0, stream>>>(Xbuf, W2, Hbuf, N, 256, 256);
    attn_simple<<<attnBlocks, 256, 0, stream>>>(Hbuf, as2, ad2, es, ed, N, 256, 64);
    hipMemsetAsync(denom, 0, (size_t)N * 16, stream);
    edge_denom<<<edgeBlocks, 256, 0, stream>>>(srcrow, dstrow, es, ed, denom, Etot, E);
    hipMemsetAsync(Xbuf, 0, (size_t)N * 256 * 4, stream);
    agg_scatter<4><<<edgeWaveBlocks, 256, 0, stream>>>(Hbuf, es, ed, denom, srcrow, dstrow,
                                                       Xbuf, Etot, E);
    epilogue<4><<<nodeWaveBlocks, 256, 0, stream>>>(Xbuf, b2, g2, be2, Xbuf, N, 1);

    // ---- layer 3: 256 -> 128 (no ELU; node_emb -> d_out f32) ----
    gemm_f32<<<dim3(2, mTiles), 256, 0, stream>>>(Xbuf, W3, Hbuf, N, 256, 128);
    attn_simple<<<attnBlocks, 256, 0, stream>>>(Hbuf, as3, ad3, es, ed, N, 128, 32);
    hipMemsetAsync(denom, 0, (size_t)N * 16, stream);
    edge_denom<<<edgeBlocks, 256, 0, stream>>>(srcrow, dstrow, es, ed, denom, Etot, E);
    hipMemsetAsync(Xbuf, 0, (size_t)N * 128 * 4, stream);
    agg_scatter<2><<<edgeWaveBlocks, 256, 0, stream>>>(Hbuf, es, ed, denom, srcrow, dstrow,
                                                       Xbuf, Etot, E);
    epilogue<2><<<nodeWaveBlocks, 256, 0, stream>>>(Xbuf, b3, g3, be3, out_node, N, 0);

    // ---- graph pooling ----
    gpool_kernel<<<(N * 128 + 255) / 256, 256, 0, stream>>>(out_node, batch, gsum, gcnt, N);
    gfinal_kernel<<<(64 * 128 + 255) / 256, 256, 0, stream>>>(gsum, gcnt, out_graph, 64);
}

// Round 8
// 1664.992 us; speedup vs baseline: 4.8524x; 4.8524x over previous
//
#include <hip/hip_runtime.h>
#include <math.h>

// ---------- helpers ----------
__device__ __forceinline__ float lrelu(float v) { return v > 0.f ? v : 0.2f * v; }

__device__ __forceinline__ float wave_allred_sum(float v) {
#pragma unroll
    for (int off = 1; off < 64; off <<= 1) v += __shfl_xor(v, off, 64);
    return v;
}

// ---------- CSR build ----------
__global__ void hist_kernel(const int* __restrict__ dstrow, int* __restrict__ cnt,
                            int Etot, int E) {
    int i = blockIdx.x * blockDim.x + threadIdx.x;
    if (i >= Etot) return;
    int d = (i < E) ? dstrow[i] : (i - E);
    atomicAdd(&cnt[d], 1);
}

__global__ void scan_kernel(const int* __restrict__ cnt, int* __restrict__ rowptr, int n) {
    __shared__ int s[1024];
    int tid = threadIdx.x;
    if (tid == 0) rowptr[0] = 0;
    int carry = 0;
    for (int base = 0; base < n; base += 1024) {
        int i = base + tid;
        int v = (i < n) ? cnt[i] : 0;
        s[tid] = v;
        __syncthreads();
        for (int off = 1; off < 1024; off <<= 1) {
            int t = (tid >= off) ? s[tid - off] : 0;
            __syncthreads();
            s[tid] += t;
            __syncthreads();
        }
        if (i < n) rowptr[i + 1] = carry + s[tid];
        int total = s[1023];
        __syncthreads();
        carry += total;
    }
}

// stores the SOURCE node id per CSR slot (one less indirection in the hot loop)
__global__ void fill_kernel(const int* __restrict__ srcrow, const int* __restrict__ dstrow,
                            const int* __restrict__ rowptr, int* __restrict__ pos,
                            int* __restrict__ srcs, int Etot, int E) {
    int i = blockIdx.x * blockDim.x + threadIdx.x;
    if (i >= Etot) return;
    int d = (i < E) ? dstrow[i] : (i - E);
    int s = (i < E) ? srcrow[i] : (i - E);
    int p = atomicAdd(&pos[d], 1);
    srcs[rowptr[d] + p] = s;
}

// ---------- tiled f32 GEMM: C[M,Nc] = A[M,K] @ B[K,Nc] ----------
__global__ __launch_bounds__(256) void gemm_f32(const float* __restrict__ A,
                                                const float* __restrict__ B,
                                                float* __restrict__ C, int M, int K, int Nc) {
    __shared__ float As[16][64];
    __shared__ float Bs[16][64];
    int tid = threadIdx.x;
    int tx = tid & 15, ty = tid >> 4;
    int m0 = blockIdx.y * 64, n0 = blockIdx.x * 64;
    int lm = tid >> 2;       // 0..63 : row within A tile
    int lk = (tid & 3) * 4;  // 0,4,8,12
    int bk = tid >> 4;       // 0..15 : row within B tile
    int bn = (tid & 15) * 4;

    float acc[4][4] = {};
    for (int kt = 0; kt < K; kt += 16) {
        int gm = m0 + lm;
        float4 av = make_float4(0.f, 0.f, 0.f, 0.f);
        if (gm < M) av = *(const float4*)(A + (size_t)gm * K + kt + lk);
        As[lk + 0][lm] = av.x; As[lk + 1][lm] = av.y;
        As[lk + 2][lm] = av.z; As[lk + 3][lm] = av.w;
        *(float4*)&Bs[bk][bn] = *(const float4*)(B + (size_t)(kt + bk) * Nc + n0 + bn);
        __syncthreads();
#pragma unroll
        for (int k = 0; k < 16; k++) {
            float4 a = *(const float4*)&As[k][ty * 4];
            float4 b = *(const float4*)&Bs[k][tx * 4];
            acc[0][0] += a.x * b.x; acc[0][1] += a.x * b.y; acc[0][2] += a.x * b.z; acc[0][3] += a.x * b.w;
            acc[1][0] += a.y * b.x; acc[1][1] += a.y * b.y; acc[1][2] += a.y * b.z; acc[1][3] += a.y * b.w;
            acc[2][0] += a.z * b.x; acc[2][1] += a.z * b.y; acc[2][2] += a.z * b.z; acc[2][3] += a.z * b.w;
            acc[3][0] += a.w * b.x; acc[3][1] += a.w * b.y; acc[3][2] += a.w * b.z; acc[3][3] += a.w * b.w;
        }
        __syncthreads();
    }
#pragma unroll
    for (int i = 0; i < 4; i++) {
        int gm = m0 + ty * 4 + i;
        if (gm < M) {
            *(float4*)&C[(size_t)gm * Nc + n0 + tx * 4] =
                make_float4(acc[i][0], acc[i][1], acc[i][2], acc[i][3]);
        }
    }
}

// ---------- attention logits: one thread per (node, head) ----------
__global__ void attn_simple(const float* __restrict__ H, const float* __restrict__ asrc,
                            const float* __restrict__ adst, float* __restrict__ es,
                            float* __restrict__ ed, int N, int HC, int C) {
    int i = blockIdx.x * blockDim.x + threadIdx.x;
    if (i >= N * 4) return;
    int node = i >> 2, hh = i & 3;
    const float* hp = H + (size_t)node * HC + hh * C;
    const float* ap = asrc + hh * C;
    const float* bp = adst + hh * C;
    float e = 0.f, d = 0.f;
    for (int c = 0; c < C; c++) {
        float h = hp[c];
        e += h * ap[c];
        d += h * bp[c];
    }
    es[i] = e;
    ed[i] = d;
}

// ---------- fused: CSR gather softmax-aggregate + bias + (ELU) + LayerNorm ----------
// one wave per destination node; lane owns channels [lane*VPL, lane*VPL+VPL)
template <int VPL>
__global__ __launch_bounds__(256) void agg_gather(
    const float* __restrict__ H, const float* __restrict__ es, const float* __restrict__ ed,
    const int* __restrict__ rowptr, const int* __restrict__ srcs,
    const float* __restrict__ bias, const float* __restrict__ gamma,
    const float* __restrict__ beta, float* __restrict__ Xout, int N, int applyElu) {
    constexpr int HC = VPL * 64;
    int lane = threadIdx.x & 63;
    int node = (blockIdx.x * blockDim.x + threadIdx.x) >> 6;
    if (node >= N) return;
    int base = rowptr[node];
    int deg = rowptr[node + 1] - base;
    float4 ed4 = *(const float4*)&ed[node * 4];

    // pass A: softmax denominator per head (lanes stride edges)
    float4 sm = make_float4(0.f, 0.f, 0.f, 0.f);
    for (int i = lane; i < deg; i += 64) {
        int s = srcs[base + i];
        float4 e4 = *(const float4*)&es[(size_t)s * 4];
        sm.x += __expf(lrelu(e4.x + ed4.x));
        sm.y += __expf(lrelu(e4.y + ed4.y));
        sm.z += __expf(lrelu(e4.z + ed4.z));
        sm.w += __expf(lrelu(e4.w + ed4.w));
    }
    sm.x = wave_allred_sum(sm.x); sm.y = wave_allred_sum(sm.y);
    sm.z = wave_allred_sum(sm.z); sm.w = wave_allred_sum(sm.w);

    int hh = lane >> 4;  // head owning this lane's channels
    float rd_h = 1.f / ((hh == 0) ? sm.x : (hh == 1) ? sm.y : (hh == 2) ? sm.z : sm.w);
    float edh = (hh == 0) ? ed4.x : (hh == 1) ? ed4.y : (hh == 2) ? ed4.z : ed4.w;

    // pass B: weighted gather (all lanes walk edges together; H rows coalesced)
    float acc[VPL];
#pragma unroll
    for (int j = 0; j < VPL; j++) acc[j] = 0.f;
    const float* Hl = H + lane * VPL;

    int i = 0;
    for (; i + 2 <= deg; i += 2) {  // 2-deep software pipeline for load latency
        int s0 = srcs[base + i];
        int s1 = srcs[base + i + 1];
        float e0 = es[(size_t)s0 * 4 + hh];
        float e1 = es[(size_t)s1 * 4 + hh];
        const float* hp0 = Hl + (size_t)s0 * HC;
        const float* hp1 = Hl + (size_t)s1 * HC;
        float a0 = __expf(lrelu(e0 + edh)) * rd_h;
        float a1 = __expf(lrelu(e1 + edh)) * rd_h;
        if constexpr (VPL == 4) {
            float4 h0 = *(const float4*)hp0;
            float4 h1 = *(const float4*)hp1;
            acc[0] += a0 * h0.x + a1 * h1.x;
            acc[1] += a0 * h0.y + a1 * h1.y;
            acc[2] += a0 * h0.z + a1 * h1.z;
            acc[3] += a0 * h0.w + a1 * h1.w;
        } else {
            float2 h0 = *(const float2*)hp0;
            float2 h1 = *(const float2*)hp1;
            acc[0] += a0 * h0.x + a1 * h1.x;
            acc[1] += a0 * h0.y + a1 * h1.y;
        }
    }
    for (; i < deg; i++) {
        int s = srcs[base + i];
        float a = __expf(lrelu(es[(size_t)s * 4 + hh] + edh)) * rd_h;
        const float* hp = Hl + (size_t)s * HC;
        if constexpr (VPL == 4) {
            float4 hv = *(const float4*)hp;
            acc[0] += a * hv.x; acc[1] += a * hv.y; acc[2] += a * hv.z; acc[3] += a * hv.w;
        } else {
            float2 hv = *(const float2*)hp;
            acc[0] += a * hv.x; acc[1] += a * hv.y;
        }
    }

    // epilogue: bias, optional ELU, LayerNorm across the wave's HC channels
    float v[VPL];
    float s1 = 0.f, s2 = 0.f;
#pragma unroll
    for (int j = 0; j < VPL; j++) {
        int ch = lane * VPL + j;
        float t = acc[j] + bias[ch];
        if (applyElu) t = (t > 0.f) ? t : (__expf(t) - 1.f);
        v[j] = t;
        s1 += t;
        s2 += t * t;
    }
    s1 = wave_allred_sum(s1);
    s2 = wave_allred_sum(s2);
    float mu = s1 / (float)HC;
    float var = s2 / (float)HC - mu * mu;
    float rs = rsqrtf(var + 1e-5f);
#pragma unroll
    for (int j = 0; j < VPL; j++) {
        int ch = lane * VPL + j;
        Xout[(size_t)node * HC + ch] = gamma[ch] * (v[j] - mu) * rs + beta[ch];
    }
}

// ---------- graph pooling ----------
__global__ void gpool_kernel(const float* __restrict__ node_emb, const int* __restrict__ batch,
                             float* __restrict__ gsum, int* __restrict__ gcnt, int N) {
    int i = blockIdx.x * blockDim.x + threadIdx.x;
    if (i >= N * 128) return;
    int node = i >> 7, ch = i & 127;
    int g = batch[node];
    atomicAdd(&gsum[g * 128 + ch], node_emb[i]);
    if (ch == 0) atomicAdd(&gcnt[g], 1);
}

__global__ void gfinal_kernel(const float* __restrict__ gsum, const int* __restrict__ gcnt,
                              float* __restrict__ out, int Gn) {
    int i = blockIdx.x * blockDim.x + threadIdx.x;
    if (i >= Gn * 128) return;
    int g = i >> 7;
    out[i] = gsum[i] / fmaxf((float)gcnt[g], 1.f);
}

// ---------- launch ----------
extern "C" void kernel_launch(void* const* d_in, const int* in_sizes, int n_in, void* d_out,
                              int out_size, void* d_ws, size_t ws_size, hipStream_t stream) {
    const float* x = (const float*)d_in[0];
    const int* ei = (const int*)d_in[1];
    const int* batch = (const int*)d_in[2];
    const float* W1 = (const float*)d_in[3];
    const float* as1 = (const float*)d_in[4];
    const float* ad1 = (const float*)d_in[5];
    const float* b1 = (const float*)d_in[6];
    const float* g1 = (const float*)d_in[7];
    const float* be1 = (const float*)d_in[8];
    const float* W2 = (const float*)d_in[9];
    const float* as2 = (const float*)d_in[10];
    const float* ad2 = (const float*)d_in[11];
    const float* b2 = (const float*)d_in[12];
    const float* g2 = (const float*)d_in[13];
    const float* be2 = (const float*)d_in[14];
    const float* W3 = (const float*)d_in[15];
    const float* as3 = (const float*)d_in[16];
    const float* ad3 = (const float*)d_in[17];
    const float* b3 = (const float*)d_in[18];
    const float* g3 = (const float*)d_in[19];
    const float* be3 = (const float*)d_in[20];

    int N = in_sizes[2];
    int E = in_sizes[1] / 2;
    int Etot = E + N;

    char* w = (char*)d_ws;
    size_t off = 0;
    auto alloc = [&](size_t bytes) -> void* {
        void* p = w + off;
        off += (bytes + 255) & ~(size_t)255;
        return p;
    };
    int* cnt = (int*)alloc((size_t)N * 4);       // | zero region (contiguous)
    int* pos = (int*)alloc((size_t)N * 4);       // |
    float* gsum = (float*)alloc(64 * 128 * 4);   // |
    int* gcnt = (int*)alloc(64 * 4);             // |
    size_t zbytes = off;
    int* rowptr = (int*)alloc((size_t)(N + 1) * 4);
    int* srcs = (int*)alloc((size_t)Etot * 4);
    float* es = (float*)alloc((size_t)N * 16);
    float* ed = (float*)alloc((size_t)N * 16);
    float* Xbuf = (float*)alloc((size_t)N * 256 * 4);
    float* Hbuf = (float*)alloc((size_t)N * 256 * 4);
    // total ≈ 108 MB

    hipMemsetAsync(d_ws, 0, zbytes, stream);

    const int* srcrow = ei;      // edge_index[0]
    const int* dstrow = ei + E;  // edge_index[1]

    int eb = (Etot + 255) / 256;
    hist_kernel<<<eb, 256, 0, stream>>>(dstrow, cnt, Etot, E);
    scan_kernel<<<1, 1024, 0, stream>>>(cnt, rowptr, N);
    fill_kernel<<<eb, 256, 0, stream>>>(srcrow, dstrow, rowptr, pos, srcs, Etot, E);

    int mTiles = (N + 63) / 64;
    int nodeWaveBlocks = (N + 3) / 4;
    int attnBlocks = (N * 4 + 255) / 256;

    float* out_node = (float*)d_out;                     // [N,128] f32
    float* out_graph = (float*)d_out + (size_t)N * 128;  // [64,128] f32

    // ---- layer 1: 768 -> 256 ----
    gemm_f32<<<dim3(4, mTiles), 256, 0, stream>>>(x, W1, Hbuf, N, 768, 256);
    attn_simple<<<attnBlocks, 256, 0, stream>>>(Hbuf, as1, ad1, es, ed, N, 256, 64);
    agg_gather<4><<<nodeWaveBlocks, 256, 0, stream>>>(Hbuf, es, ed, rowptr, srcs, b1, g1, be1,
                                                      Xbuf, N, 1);
    // ---- layer 2: 256 -> 256 ----
    gemm_f32<<<dim3(4, mTiles), 256, 0, stream>>>(Xbuf, W2, Hbuf, N, 256, 256);
    attn_simple<<<attnBlocks, 256, 0, stream>>>(Hbuf, as2, ad2, es, ed, N, 256, 64);
    agg_gather<4><<<nodeWaveBlocks, 256, 0, stream>>>(Hbuf, es, ed, rowptr, srcs, b2, g2, be2,
                                                      Xbuf, N, 1);
    // ---- layer 3: 256 -> 128 (no ELU; node_emb -> d_out f32) ----
    gemm_f32<<<dim3(2, mTiles), 256, 0, stream>>>(Xbuf, W3, Hbuf, N, 256, 128);
    attn_simple<<<attnBlocks, 256, 0, stream>>>(Hbuf, as3, ad3, es, ed, N, 128, 32);
    agg_gather<2><<<nodeWaveBlocks, 256, 0, stream>>>(Hbuf, es, ed, rowptr, srcs, b3, g3, be3,
                                                      out_node, N, 0);
    // ---- graph pooling ----
    gpool_kernel<<<(N * 128 + 255) / 256, 256, 0, stream>>>(out_node, batch, gsum, gcnt, N);
    gfinal_kernel<<<(64 * 128 + 255) / 256, 256, 0, stream>>>(gsum, gcnt, out_graph, 64);
}

// Round 9
// 1027.982 us; speedup vs baseline: 7.8592x; 1.6197x over previous
//
#include <hip/hip_runtime.h>
#include <math.h>

// ---------- helpers ----------
__device__ __forceinline__ float lrelu(float v) { return v > 0.f ? v : 0.2f * v; }
__device__ __forceinline__ ushort f2bf(float f) {
    unsigned int x = __float_as_uint(f);
    return (ushort)((x + 0x7fffu + ((x >> 16) & 1u)) >> 16);
}
__device__ __forceinline__ float wave_allred_sum(float v) {
#pragma unroll
    for (int off = 1; off < 64; off <<= 1) v += __shfl_xor(v, off, 64);
    return v;
}

typedef short bf16x8 __attribute__((ext_vector_type(8)));
typedef float f32x4 __attribute__((ext_vector_type(4)));

// ---------- CSR build ----------
__global__ void hist_kernel(const int* __restrict__ dstrow, int* __restrict__ cnt,
                            int Etot, int E) {
    int i = blockIdx.x * blockDim.x + threadIdx.x;
    if (i >= Etot) return;
    int d = (i < E) ? dstrow[i] : (i - E);
    atomicAdd(&cnt[d], 1);
}

// blocked scan: K1 per-block inclusive scan + block totals
__global__ __launch_bounds__(256) void scan1_kernel(const int* __restrict__ cnt,
                                                    int* __restrict__ out,
                                                    int* __restrict__ btot, int n) {
    __shared__ int s[256];
    int i = blockIdx.x * 256 + threadIdx.x;
    int v = (i < n) ? cnt[i] : 0;
    s[threadIdx.x] = v;
    __syncthreads();
    for (int off = 1; off < 256; off <<= 1) {
        int t = (threadIdx.x >= off) ? s[threadIdx.x - off] : 0;
        __syncthreads();
        s[threadIdx.x] += t;
        __syncthreads();
    }
    if (i < n) out[i] = s[threadIdx.x];
    if (threadIdx.x == 255) btot[blockIdx.x] = s[255];
}
// K2: single-block exclusive scan of block totals (nb <= 1024)
__global__ __launch_bounds__(1024) void scan2_kernel(int* __restrict__ btot, int nb) {
    __shared__ int s[1024];
    int tid = threadIdx.x;
    int v = (tid < nb) ? btot[tid] : 0;
    s[tid] = v;
    __syncthreads();
    for (int off = 1; off < 1024; off <<= 1) {
        int t = (tid >= off) ? s[tid - off] : 0;
        __syncthreads();
        s[tid] += t;
        __syncthreads();
    }
    if (tid < nb) btot[tid] = s[tid] - v;  // exclusive
}
// K3: add back offsets -> rowptr
__global__ void scan3_kernel(const int* __restrict__ scanned, const int* __restrict__ btot,
                             int* __restrict__ rowptr, int n) {
    int i = blockIdx.x * 256 + threadIdx.x;
    if (i < n) rowptr[i + 1] = scanned[i] + btot[i >> 8];
    if (i == 0) rowptr[0] = 0;
}

// stores the SOURCE node id per CSR slot
__global__ void fill_kernel(const int* __restrict__ srcrow, const int* __restrict__ dstrow,
                            const int* __restrict__ rowptr, int* __restrict__ pos,
                            int* __restrict__ srcs, int Etot, int E) {
    int i = blockIdx.x * blockDim.x + threadIdx.x;
    if (i >= Etot) return;
    int d = (i < E) ? dstrow[i] : (i - E);
    int s = (i < E) ? srcrow[i] : (i - E);
    int p = atomicAdd(&pos[d], 1);
    srcs[rowptr[d] + p] = s;
}

// ---------- MFMA GEMM: C[M,N](f32) = A[M,K](f32) @ B[K,N](f32), bf16 internal ----------
// block 256 = 4 waves; tile 128x128, BK=32. Wave w: rows [w*32,w*32+32) -> 2x8 MFMA tiles.
__global__ __launch_bounds__(256) void gemm_mfma(const float* __restrict__ A,
                                                 const float* __restrict__ B,
                                                 float* __restrict__ C, int M, int K, int N) {
    __shared__ ushort As[128][40];  // [m][k], pitch 40 (bank spread, 16B-aligned rows)
    __shared__ ushort Bs[128][40];  // [n][k], transposed in staging
    int tid = threadIdx.x;
    int wave = tid >> 6, lane = tid & 63;
    int m0 = blockIdx.y * 128, n0 = blockIdx.x * 128;

    f32x4 acc[2][8] = {};

    int arow = tid >> 1;          // 0..127
    int ak = (tid & 1) * 16;      // 0 or 16
    int bk = tid >> 3;            // 0..31
    int bn = (tid & 7) * 16;      // 0..112

    int quad = lane >> 4;
    int mrow = lane & 15;

    for (int kt = 0; kt < K; kt += 32) {
        // stage A (f32 -> bf16)
        if (m0 + arow < M) {
            const float* p = A + (size_t)(m0 + arow) * K + kt + ak;
#pragma unroll
            for (int q = 0; q < 4; q++) {
                float4 v = *(const float4*)(p + q * 4);
                ushort* d = &As[arow][ak + q * 4];
                d[0] = f2bf(v.x); d[1] = f2bf(v.y); d[2] = f2bf(v.z); d[3] = f2bf(v.w);
            }
        } else {
#pragma unroll
            for (int q = 0; q < 16; q++) As[arow][ak + q] = 0;
        }
        // stage B transposed (f32 -> bf16): Bs[n][k]
        {
            const float* p = B + (size_t)(kt + bk) * N + n0 + bn;
#pragma unroll
            for (int q = 0; q < 4; q++) {
                float4 v = *(const float4*)(p + q * 4);
                Bs[bn + q * 4 + 0][bk] = f2bf(v.x);
                Bs[bn + q * 4 + 1][bk] = f2bf(v.y);
                Bs[bn + q * 4 + 2][bk] = f2bf(v.z);
                Bs[bn + q * 4 + 3][bk] = f2bf(v.w);
            }
        }
        __syncthreads();
        bf16x8 afrag[2], bfrag[8];
#pragma unroll
        for (int r = 0; r < 2; r++)
            afrag[r] = *(const bf16x8*)&As[wave * 32 + r * 16 + mrow][quad * 8];
#pragma unroll
        for (int c = 0; c < 8; c++)
            bfrag[c] = *(const bf16x8*)&Bs[c * 16 + mrow][quad * 8];
#pragma unroll
        for (int r = 0; r < 2; r++)
#pragma unroll
            for (int c = 0; c < 8; c++)
                acc[r][c] = __builtin_amdgcn_mfma_f32_16x16x32_bf16(afrag[r], bfrag[c],
                                                                    acc[r][c], 0, 0, 0);
        __syncthreads();
    }
    // epilogue: C/D layout col=lane&15, row=quad*4+reg
    int col = lane & 15;
#pragma unroll
    for (int r = 0; r < 2; r++) {
#pragma unroll
        for (int c = 0; c < 8; c++) {
#pragma unroll
            for (int reg = 0; reg < 4; reg++) {
                int gm = m0 + wave * 32 + r * 16 + quad * 4 + reg;
                int gn = n0 + c * 16 + col;
                if (gm < M) C[(size_t)gm * N + gn] = acc[r][c][reg];
            }
        }
    }
}

// ---------- attention logits: one thread per (node, head) ----------
__global__ void attn_simple(const float* __restrict__ H, const float* __restrict__ asrc,
                            const float* __restrict__ adst, float* __restrict__ es,
                            float* __restrict__ ed, int N, int HC, int C) {
    int i = blockIdx.x * blockDim.x + threadIdx.x;
    if (i >= N * 4) return;
    int node = i >> 2, hh = i & 3;
    const float* hp = H + (size_t)node * HC + hh * C;
    const float* ap = asrc + hh * C;
    const float* bp = adst + hh * C;
    float e = 0.f, d = 0.f;
    for (int c = 0; c < C; c++) {
        float h = hp[c];
        e += h * ap[c];
        d += h * bp[c];
    }
    es[i] = e;
    ed[i] = d;
}

// ---------- fused CSR-gather softmax-aggregate + bias + (ELU) + LayerNorm ----------
template <int VPL>
__global__ __launch_bounds__(256) void agg_gather(
    const float* __restrict__ H, const float* __restrict__ es, const float* __restrict__ ed,
    const int* __restrict__ rowptr, const int* __restrict__ srcs,
    const float* __restrict__ bias, const float* __restrict__ gamma,
    const float* __restrict__ beta, float* __restrict__ Xout, int N, int applyElu) {
    constexpr int HC = VPL * 64;
    int lane = threadIdx.x & 63;
    int node = (blockIdx.x * blockDim.x + threadIdx.x) >> 6;
    if (node >= N) return;
    int base = rowptr[node];
    int deg = rowptr[node + 1] - base;
    float4 ed4 = *(const float4*)&ed[node * 4];

    float4 sm = make_float4(0.f, 0.f, 0.f, 0.f);
    for (int i = lane; i < deg; i += 64) {
        int s = srcs[base + i];
        float4 e4 = *(const float4*)&es[(size_t)s * 4];
        sm.x += __expf(lrelu(e4.x + ed4.x));
        sm.y += __expf(lrelu(e4.y + ed4.y));
        sm.z += __expf(lrelu(e4.z + ed4.z));
        sm.w += __expf(lrelu(e4.w + ed4.w));
    }
    sm.x = wave_allred_sum(sm.x); sm.y = wave_allred_sum(sm.y);
    sm.z = wave_allred_sum(sm.z); sm.w = wave_allred_sum(sm.w);

    int hh = lane >> 4;
    float rd_h = 1.f / ((hh == 0) ? sm.x : (hh == 1) ? sm.y : (hh == 2) ? sm.z : sm.w);
    float edh = (hh == 0) ? ed4.x : (hh == 1) ? ed4.y : (hh == 2) ? ed4.z : ed4.w;

    float acc[VPL];
#pragma unroll
    for (int j = 0; j < VPL; j++) acc[j] = 0.f;
    const float* Hl = H + lane * VPL;

    int i = 0;
    for (; i + 2 <= deg; i += 2) {
        int s0 = srcs[base + i];
        int s1 = srcs[base + i + 1];
        float e0 = es[(size_t)s0 * 4 + hh];
        float e1 = es[(size_t)s1 * 4 + hh];
        const float* hp0 = Hl + (size_t)s0 * HC;
        const float* hp1 = Hl + (size_t)s1 * HC;
        float a0 = __expf(lrelu(e0 + edh)) * rd_h;
        float a1 = __expf(lrelu(e1 + edh)) * rd_h;
        if constexpr (VPL == 4) {
            float4 h0 = *(const float4*)hp0;
            float4 h1 = *(const float4*)hp1;
            acc[0] += a0 * h0.x + a1 * h1.x;
            acc[1] += a0 * h0.y + a1 * h1.y;
            acc[2] += a0 * h0.z + a1 * h1.z;
            acc[3] += a0 * h0.w + a1 * h1.w;
        } else {
            float2 h0 = *(const float2*)hp0;
            float2 h1 = *(const float2*)hp1;
            acc[0] += a0 * h0.x + a1 * h1.x;
            acc[1] += a0 * h0.y + a1 * h1.y;
        }
    }
    for (; i < deg; i++) {
        int s = srcs[base + i];
        float a = __expf(lrelu(es[(size_t)s * 4 + hh] + edh)) * rd_h;
        const float* hp = Hl + (size_t)s * HC;
        if constexpr (VPL == 4) {
            float4 hv = *(const float4*)hp;
            acc[0] += a * hv.x; acc[1] += a * hv.y; acc[2] += a * hv.z; acc[3] += a * hv.w;
        } else {
            float2 hv = *(const float2*)hp;
            acc[0] += a * hv.x; acc[1] += a * hv.y;
        }
    }

    float v[VPL];
    float s1 = 0.f, s2 = 0.f;
#pragma unroll
    for (int j = 0; j < VPL; j++) {
        int ch = lane * VPL + j;
        float t = acc[j] + bias[ch];
        if (applyElu) t = (t > 0.f) ? t : (__expf(t) - 1.f);
        v[j] = t;
        s1 += t;
        s2 += t * t;
    }
    s1 = wave_allred_sum(s1);
    s2 = wave_allred_sum(s2);
    float mu = s1 / (float)HC;
    float var = s2 / (float)HC - mu * mu;
    float rs = rsqrtf(var + 1e-5f);
#pragma unroll
    for (int j = 0; j < VPL; j++) {
        int ch = lane * VPL + j;
        Xout[(size_t)node * HC + ch] = gamma[ch] * (v[j] - mu) * rs + beta[ch];
    }
}

// ---------- graph pooling: sorted-run flush (batch is sorted) ----------
__global__ __launch_bounds__(128) void gsum_kernel(const float* __restrict__ node_emb,
                                                   const int* __restrict__ batch,
                                                   float* __restrict__ gsum,
                                                   int* __restrict__ gcnt, int N) {
    int start = blockIdx.x * 256;
    if (start >= N) return;
    int end = min(start + 256, N);
    int ch = threadIdx.x;
    float acc = 0.f;
    int runlen = 0;
    int curg = batch[start];
    for (int n = start; n < end; n++) {
        int g = batch[n];
        if (g != curg) {
            atomicAdd(&gsum[curg * 128 + ch], acc);
            if (ch == 0) atomicAdd(&gcnt[curg], runlen);
            acc = 0.f; runlen = 0; curg = g;
        }
        acc += node_emb[(size_t)n * 128 + ch];
        runlen++;
    }
    atomicAdd(&gsum[curg * 128 + ch], acc);
    if (ch == 0) atomicAdd(&gcnt[curg], runlen);
}

__global__ void gfinal_kernel(const float* __restrict__ gsum, const int* __restrict__ gcnt,
                              float* __restrict__ out, int Gn) {
    int i = blockIdx.x * blockDim.x + threadIdx.x;
    if (i >= Gn * 128) return;
    int g = i >> 7;
    out[i] = gsum[i] / fmaxf((float)gcnt[g], 1.f);
}

// ---------- launch ----------
extern "C" void kernel_launch(void* const* d_in, const int* in_sizes, int n_in, void* d_out,
                              int out_size, void* d_ws, size_t ws_size, hipStream_t stream) {
    const float* x = (const float*)d_in[0];
    const int* ei = (const int*)d_in[1];
    const int* batch = (const int*)d_in[2];
    const float* W1 = (const float*)d_in[3];
    const float* as1 = (const float*)d_in[4];
    const float* ad1 = (const float*)d_in[5];
    const float* b1 = (const float*)d_in[6];
    const float* g1 = (const float*)d_in[7];
    const float* be1 = (const float*)d_in[8];
    const float* W2 = (const float*)d_in[9];
    const float* as2 = (const float*)d_in[10];
    const float* ad2 = (const float*)d_in[11];
    const float* b2 = (const float*)d_in[12];
    const float* g2 = (const float*)d_in[13];
    const float* be2 = (const float*)d_in[14];
    const float* W3 = (const float*)d_in[15];
    const float* as3 = (const float*)d_in[16];
    const float* ad3 = (const float*)d_in[17];
    const float* b3 = (const float*)d_in[18];
    const float* g3 = (const float*)d_in[19];
    const float* be3 = (const float*)d_in[20];

    int N = in_sizes[2];
    int E = in_sizes[1] / 2;
    int Etot = E + N;

    char* w = (char*)d_ws;
    size_t off = 0;
    auto alloc = [&](size_t bytes) -> void* {
        void* p = w + off;
        off += (bytes + 255) & ~(size_t)255;
        return p;
    };
    int* cnt = (int*)alloc((size_t)N * 4);       // | zero region
    int* pos = (int*)alloc((size_t)N * 4);       // |
    float* gsum = (float*)alloc(64 * 128 * 4);   // |
    int* gcnt = (int*)alloc(64 * 4);             // |
    size_t zbytes = off;
    int* scantmp = (int*)alloc((size_t)N * 4);
    int* btot = (int*)alloc(1024 * 4);
    int* rowptr = (int*)alloc((size_t)(N + 1) * 4);
    int* srcs = (int*)alloc((size_t)Etot * 4);
    float* es = (float*)alloc((size_t)N * 16);
    float* ed = (float*)alloc((size_t)N * 16);
    float* Xbuf = (float*)alloc((size_t)N * 256 * 4);
    float* Hbuf = (float*)alloc((size_t)N * 256 * 4);

    hipMemsetAsync(d_ws, 0, zbytes, stream);

    const int* srcrow = ei;
    const int* dstrow = ei + E;

    int eb = (Etot + 255) / 256;
    int nb = (N + 255) / 256;
    hist_kernel<<<eb, 256, 0, stream>>>(dstrow, cnt, Etot, E);
    scan1_kernel<<<nb, 256, 0, stream>>>(cnt, scantmp, btot, N);
    scan2_kernel<<<1, 1024, 0, stream>>>(btot, nb);
    scan3_kernel<<<nb, 256, 0, stream>>>(scantmp, btot, rowptr, N);
    fill_kernel<<<eb, 256, 0, stream>>>(srcrow, dstrow, rowptr, pos, srcs, Etot, E);

    int mT = (N + 127) / 128;
    int nodeWaveBlocks = (N + 3) / 4;
    int attnBlocks = (N * 4 + 255) / 256;

    float* out_node = (float*)d_out;                     // [N,128] f32
    float* out_graph = (float*)d_out + (size_t)N * 128;  // [64,128] f32

    // ---- layer 1: 768 -> 256 ----
    gemm_mfma<<<dim3(2, mT), 256, 0, stream>>>(x, W1, Hbuf, N, 768, 256);
    attn_simple<<<attnBlocks, 256, 0, stream>>>(Hbuf, as1, ad1, es, ed, N, 256, 64);
    agg_gather<4><<<nodeWaveBlocks, 256, 0, stream>>>(Hbuf, es, ed, rowptr, srcs, b1, g1, be1,
                                                      Xbuf, N, 1);
    // ---- layer 2: 256 -> 256 ----
    gemm_mfma<<<dim3(2, mT), 256, 0, stream>>>(Xbuf, W2, Hbuf, N, 256, 256);
    attn_simple<<<attnBlocks, 256, 0, stream>>>(Hbuf, as2, ad2, es, ed, N, 256, 64);
    agg_gather<4><<<nodeWaveBlocks, 256, 0, stream>>>(Hbuf, es, ed, rowptr, srcs, b2, g2, be2,
                                                      Xbuf, N, 1);
    // ---- layer 3: 256 -> 128 (no ELU; node_emb -> d_out f32) ----
    gemm_mfma<<<dim3(1, mT), 256, 0, stream>>>(Xbuf, W3, Hbuf, N, 256, 128);
    attn_simple<<<attnBlocks, 256, 0, stream>>>(Hbuf, as3, ad3, es, ed, N, 128, 32);
    agg_gather<2><<<nodeWaveBlocks, 256, 0, stream>>>(Hbuf, es, ed, rowptr, srcs, b3, g3, be3,
                                                      out_node, N, 0);
    // ---- graph pooling ----
    gsum_kernel<<<(N + 255) / 256, 128, 0, stream>>>(out_node, batch, gsum, gcnt, N);
    gfinal_kernel<<<(64 * 128 + 255) / 256, 256, 0, stream>>>(gsum, gcnt, out_graph, 64);
}

// Round 10
// 820.401 us; speedup vs baseline: 9.8478x; 1.2530x over previous
//
#include <hip/hip_runtime.h>
#include <math.h>

// ---------- helpers ----------
__device__ __forceinline__ float lrelu(float v) { return v > 0.f ? v : 0.2f * v; }
__device__ __forceinline__ float bf2f(ushort u) {
    return __uint_as_float(((unsigned int)u) << 16);
}
__device__ __forceinline__ ushort f2bf(float f) {
    unsigned int x = __float_as_uint(f);
    return (ushort)((x + 0x7fffu + ((x >> 16) & 1u)) >> 16);
}
__device__ __forceinline__ float wave_allred_sum(float v) {
#pragma unroll
    for (int off = 1; off < 64; off <<= 1) v += __shfl_xor(v, off, 64);
    return v;
}

typedef short bf16x8 __attribute__((ext_vector_type(8)));
typedef float f32x4 __attribute__((ext_vector_type(4)));

// ---------- CSR build ----------
__global__ void hist_kernel(const int* __restrict__ dstrow, int* __restrict__ cnt,
                            int Etot, int E) {
    int i = blockIdx.x * blockDim.x + threadIdx.x;
    if (i >= Etot) return;
    int d = (i < E) ? dstrow[i] : (i - E);
    atomicAdd(&cnt[d], 1);
}

__global__ __launch_bounds__(256) void scan1_kernel(const int* __restrict__ cnt,
                                                    int* __restrict__ out,
                                                    int* __restrict__ btot, int n) {
    __shared__ int s[256];
    int i = blockIdx.x * 256 + threadIdx.x;
    int v = (i < n) ? cnt[i] : 0;
    s[threadIdx.x] = v;
    __syncthreads();
    for (int off = 1; off < 256; off <<= 1) {
        int t = (threadIdx.x >= off) ? s[threadIdx.x - off] : 0;
        __syncthreads();
        s[threadIdx.x] += t;
        __syncthreads();
    }
    if (i < n) out[i] = s[threadIdx.x];
    if (threadIdx.x == 255) btot[blockIdx.x] = s[255];
}
__global__ __launch_bounds__(1024) void scan2_kernel(int* __restrict__ btot, int nb) {
    __shared__ int s[1024];
    int tid = threadIdx.x;
    int v = (tid < nb) ? btot[tid] : 0;
    s[tid] = v;
    __syncthreads();
    for (int off = 1; off < 1024; off <<= 1) {
        int t = (tid >= off) ? s[tid - off] : 0;
        __syncthreads();
        s[tid] += t;
        __syncthreads();
    }
    if (tid < nb) btot[tid] = s[tid] - v;  // exclusive
}
__global__ void scan3_kernel(const int* __restrict__ scanned, const int* __restrict__ btot,
                             int* __restrict__ rowptr, int n) {
    int i = blockIdx.x * 256 + threadIdx.x;
    if (i < n) rowptr[i + 1] = scanned[i] + btot[i >> 8];
    if (i == 0) rowptr[0] = 0;
}

__global__ void fill_kernel(const int* __restrict__ srcrow, const int* __restrict__ dstrow,
                            const int* __restrict__ rowptr, int* __restrict__ pos,
                            int* __restrict__ srcs, int Etot, int E) {
    int i = blockIdx.x * blockDim.x + threadIdx.x;
    if (i >= Etot) return;
    int d = (i < E) ? dstrow[i] : (i - E);
    int s = (i < E) ? srcrow[i] : (i - E);
    int p = atomicAdd(&pos[d], 1);
    srcs[rowptr[d] + p] = s;
}

// ---------- MFMA GEMM: C[M,N](bf16) = A[M,K](f32|bf16) @ B[K,N](f32), f32 accum ----------
// block 256 = 4 waves; tile 128x128, BK=32.
template <typename TA>
__global__ __launch_bounds__(256) void gemm_mfma(const TA* __restrict__ A,
                                                 const float* __restrict__ B,
                                                 ushort* __restrict__ C, int M, int K, int N) {
    __shared__ ushort As[128][40];  // [m][k], pitch 40 (multiple of 8 -> 16B-aligned rows)
    __shared__ ushort Bs[128][40];  // [n][k], transposed in staging
    int tid = threadIdx.x;
    int wave = tid >> 6, lane = tid & 63;
    int m0 = blockIdx.y * 128, n0 = blockIdx.x * 128;

    f32x4 acc[2][8] = {};

    int arow = tid >> 1;          // 0..127
    int ak = (tid & 1) * 16;      // 0 or 16
    int bk = tid >> 3;            // 0..31
    int bn = (tid & 7) * 16;      // 0..112

    int quad = lane >> 4;
    int mrow = lane & 15;

    for (int kt = 0; kt < K; kt += 32) {
        // stage A -> bf16
        if (m0 + arow < M) {
            if constexpr (sizeof(TA) == 4) {
                const float* p = (const float*)A + (size_t)(m0 + arow) * K + kt + ak;
#pragma unroll
                for (int q = 0; q < 4; q++) {
                    float4 v = *(const float4*)(p + q * 4);
                    ushort* d = &As[arow][ak + q * 4];
                    d[0] = f2bf(v.x); d[1] = f2bf(v.y); d[2] = f2bf(v.z); d[3] = f2bf(v.w);
                }
            } else {
                const ushort* p = (const ushort*)A + (size_t)(m0 + arow) * K + kt + ak;
                *(uint4*)&As[arow][ak] = *(const uint4*)p;
                *(uint4*)&As[arow][ak + 8] = *(const uint4*)(p + 8);
            }
        } else {
#pragma unroll
            for (int q = 0; q < 16; q++) As[arow][ak + q] = 0;
        }
        // stage B transposed (f32 -> bf16): Bs[n][k]
        {
            const float* p = B + (size_t)(kt + bk) * N + n0 + bn;
#pragma unroll
            for (int q = 0; q < 4; q++) {
                float4 v = *(const float4*)(p + q * 4);
                Bs[bn + q * 4 + 0][bk] = f2bf(v.x);
                Bs[bn + q * 4 + 1][bk] = f2bf(v.y);
                Bs[bn + q * 4 + 2][bk] = f2bf(v.z);
                Bs[bn + q * 4 + 3][bk] = f2bf(v.w);
            }
        }
        __syncthreads();
        bf16x8 afrag[2], bfrag[8];
#pragma unroll
        for (int r = 0; r < 2; r++)
            afrag[r] = *(const bf16x8*)&As[wave * 32 + r * 16 + mrow][quad * 8];
#pragma unroll
        for (int c = 0; c < 8; c++)
            bfrag[c] = *(const bf16x8*)&Bs[c * 16 + mrow][quad * 8];
#pragma unroll
        for (int r = 0; r < 2; r++)
#pragma unroll
            for (int c = 0; c < 8; c++)
                acc[r][c] = __builtin_amdgcn_mfma_f32_16x16x32_bf16(afrag[r], bfrag[c],
                                                                    acc[r][c], 0, 0, 0);
        __syncthreads();
    }
    // epilogue: C/D layout col=lane&15, row=quad*4+reg
    int col = lane & 15;
#pragma unroll
    for (int r = 0; r < 2; r++) {
#pragma unroll
        for (int c = 0; c < 8; c++) {
#pragma unroll
            for (int reg = 0; reg < 4; reg++) {
                int gm = m0 + wave * 32 + r * 16 + quad * 4 + reg;
                int gn = n0 + c * 16 + col;
                if (gm < M) C[(size_t)gm * N + gn] = f2bf(acc[r][c][reg]);
            }
        }
    }
}

// ---------- attention logits: one wave per node, bf16 H ----------
template <int VPL>
__global__ __launch_bounds__(256) void attn_wave(const ushort* __restrict__ H,
                                                 const float* __restrict__ asrc,
                                                 const float* __restrict__ adst,
                                                 float* __restrict__ es, float* __restrict__ ed,
                                                 int N) {
    constexpr int HC = VPL * 64;
    int lane = threadIdx.x & 63;
    int node = (blockIdx.x * blockDim.x + threadIdx.x) >> 6;
    if (node >= N) return;
    const ushort* hp = H + (size_t)node * HC + lane * VPL;
    float esum = 0.f, dsum = 0.f;
#pragma unroll
    for (int j = 0; j < VPL; j++) {
        float h = bf2f(hp[j]);
        int ch = lane * VPL + j;
        esum += h * asrc[ch];
        dsum += h * adst[ch];
    }
#pragma unroll
    for (int off = 1; off < 16; off <<= 1) {
        esum += __shfl_xor(esum, off, 64);
        dsum += __shfl_xor(dsum, off, 64);
    }
    if ((lane & 15) == 0) {
        int hh = lane >> 4;
        es[node * 4 + hh] = esum;
        ed[node * 4 + hh] = dsum;
    }
}

// ---------- fused CSR-gather softmax-aggregate + bias + (ELU) + LayerNorm ----------
// bf16 H rows; output bf16 (XoutB) for inter-layer, f32 (XoutF) for final node_emb.
template <int VPL>
__global__ __launch_bounds__(256) void agg_gather(
    const ushort* __restrict__ H, const float* __restrict__ es, const float* __restrict__ ed,
    const int* __restrict__ rowptr, const int* __restrict__ srcs,
    const float* __restrict__ bias, const float* __restrict__ gamma,
    const float* __restrict__ beta, ushort* __restrict__ XoutB, float* __restrict__ XoutF,
    int N, int applyElu) {
    constexpr int HC = VPL * 64;
    int lane = threadIdx.x & 63;
    int node = (blockIdx.x * blockDim.x + threadIdx.x) >> 6;
    if (node >= N) return;
    int base = rowptr[node];
    int deg = rowptr[node + 1] - base;
    float4 ed4 = *(const float4*)&ed[node * 4];

    // pass A: softmax denominator per head
    float4 sm = make_float4(0.f, 0.f, 0.f, 0.f);
    for (int i = lane; i < deg; i += 64) {
        int s = srcs[base + i];
        float4 e4 = *(const float4*)&es[(size_t)s * 4];
        sm.x += __expf(lrelu(e4.x + ed4.x));
        sm.y += __expf(lrelu(e4.y + ed4.y));
        sm.z += __expf(lrelu(e4.z + ed4.z));
        sm.w += __expf(lrelu(e4.w + ed4.w));
    }
    sm.x = wave_allred_sum(sm.x); sm.y = wave_allred_sum(sm.y);
    sm.z = wave_allred_sum(sm.z); sm.w = wave_allred_sum(sm.w);

    int hh = lane >> 4;
    float rd_h = 1.f / ((hh == 0) ? sm.x : (hh == 1) ? sm.y : (hh == 2) ? sm.z : sm.w);
    float edh = (hh == 0) ? ed4.x : (hh == 1) ? ed4.y : (hh == 2) ? ed4.z : ed4.w;

    // pass B: weighted gather of bf16 rows
    float acc[VPL];
#pragma unroll
    for (int j = 0; j < VPL; j++) acc[j] = 0.f;
    const ushort* Hl = H + lane * VPL;

    int i = 0;
    for (; i + 2 <= deg; i += 2) {
        int s0 = srcs[base + i];
        int s1 = srcs[base + i + 1];
        float e0 = es[(size_t)s0 * 4 + hh];
        float e1 = es[(size_t)s1 * 4 + hh];
        const ushort* hp0 = Hl + (size_t)s0 * HC;
        const ushort* hp1 = Hl + (size_t)s1 * HC;
        float a0 = __expf(lrelu(e0 + edh)) * rd_h;
        float a1 = __expf(lrelu(e1 + edh)) * rd_h;
        if constexpr (VPL == 4) {
            ushort4 h0 = *(const ushort4*)hp0;
            ushort4 h1 = *(const ushort4*)hp1;
            acc[0] += a0 * bf2f(h0.x) + a1 * bf2f(h1.x);
            acc[1] += a0 * bf2f(h0.y) + a1 * bf2f(h1.y);
            acc[2] += a0 * bf2f(h0.z) + a1 * bf2f(h1.z);
            acc[3] += a0 * bf2f(h0.w) + a1 * bf2f(h1.w);
        } else {
            ushort2 h0 = *(const ushort2*)hp0;
            ushort2 h1 = *(const ushort2*)hp1;
            acc[0] += a0 * bf2f(h0.x) + a1 * bf2f(h1.x);
            acc[1] += a0 * bf2f(h0.y) + a1 * bf2f(h1.y);
        }
    }
    for (; i < deg; i++) {
        int s = srcs[base + i];
        float a = __expf(lrelu(es[(size_t)s * 4 + hh] + edh)) * rd_h;
        const ushort* hp = Hl + (size_t)s * HC;
        if constexpr (VPL == 4) {
            ushort4 hv = *(const ushort4*)hp;
            acc[0] += a * bf2f(hv.x); acc[1] += a * bf2f(hv.y);
            acc[2] += a * bf2f(hv.z); acc[3] += a * bf2f(hv.w);
        } else {
            ushort2 hv = *(const ushort2*)hp;
            acc[0] += a * bf2f(hv.x); acc[1] += a * bf2f(hv.y);
        }
    }

    // epilogue: bias, optional ELU, LayerNorm
    float v[VPL];
    float s1 = 0.f, s2 = 0.f;
#pragma unroll
    for (int j = 0; j < VPL; j++) {
        int ch = lane * VPL + j;
        float t = acc[j] + bias[ch];
        if (applyElu) t = (t > 0.f) ? t : (__expf(t) - 1.f);
        v[j] = t;
        s1 += t;
        s2 += t * t;
    }
    s1 = wave_allred_sum(s1);
    s2 = wave_allred_sum(s2);
    float mu = s1 / (float)HC;
    float var = s2 / (float)HC - mu * mu;
    float rs = rsqrtf(var + 1e-5f);
#pragma unroll
    for (int j = 0; j < VPL; j++) {
        int ch = lane * VPL + j;
        float o = gamma[ch] * (v[j] - mu) * rs + beta[ch];
        if (XoutF) XoutF[(size_t)node * HC + ch] = o;
        else XoutB[(size_t)node * HC + ch] = f2bf(o);
    }
}

// ---------- graph pooling: sorted-run flush ----------
__global__ __launch_bounds__(128) void gsum_kernel(const float* __restrict__ node_emb,
                                                   const int* __restrict__ batch,
                                                   float* __restrict__ gsum,
                                                   int* __restrict__ gcnt, int N) {
    int start = blockIdx.x * 256;
    if (start >= N) return;
    int end = min(start + 256, N);
    int ch = threadIdx.x;
    float acc = 0.f;
    int runlen = 0;
    int curg = batch[start];
    for (int n = start; n < end; n++) {
        int g = batch[n];
        if (g != curg) {
            atomicAdd(&gsum[curg * 128 + ch], acc);
            if (ch == 0) atomicAdd(&gcnt[curg], runlen);
            acc = 0.f; runlen = 0; curg = g;
        }
        acc += node_emb[(size_t)n * 128 + ch];
        runlen++;
    }
    atomicAdd(&gsum[curg * 128 + ch], acc);
    if (ch == 0) atomicAdd(&gcnt[curg], runlen);
}

__global__ void gfinal_kernel(const float* __restrict__ gsum, const int* __restrict__ gcnt,
                              float* __restrict__ out, int Gn) {
    int i = blockIdx.x * blockDim.x + threadIdx.x;
    if (i >= Gn * 128) return;
    int g = i >> 7;
    out[i] = gsum[i] / fmaxf((float)gcnt[g], 1.f);
}

// ---------- launch ----------
extern "C" void kernel_launch(void* const* d_in, const int* in_sizes, int n_in, void* d_out,
                              int out_size, void* d_ws, size_t ws_size, hipStream_t stream) {
    const float* x = (const float*)d_in[0];
    const int* ei = (const int*)d_in[1];
    const int* batch = (const int*)d_in[2];
    const float* W1 = (const float*)d_in[3];
    const float* as1 = (const float*)d_in[4];
    const float* ad1 = (const float*)d_in[5];
    const float* b1 = (const float*)d_in[6];
    const float* g1 = (const float*)d_in[7];
    const float* be1 = (const float*)d_in[8];
    const float* W2 = (const float*)d_in[9];
    const float* as2 = (const float*)d_in[10];
    const float* ad2 = (const float*)d_in[11];
    const float* b2 = (const float*)d_in[12];
    const float* g2 = (const float*)d_in[13];
    const float* be2 = (const float*)d_in[14];
    const float* W3 = (const float*)d_in[15];
    const float* as3 = (const float*)d_in[16];
    const float* ad3 = (const float*)d_in[17];
    const float* b3 = (const float*)d_in[18];
    const float* g3 = (const float*)d_in[19];
    const float* be3 = (const float*)d_in[20];

    int N = in_sizes[2];
    int E = in_sizes[1] / 2;
    int Etot = E + N;

    char* w = (char*)d_ws;
    size_t off = 0;
    auto alloc = [&](size_t bytes) -> void* {
        void* p = w + off;
        off += (bytes + 255) & ~(size_t)255;
        return p;
    };
    int* cnt = (int*)alloc((size_t)N * 4);       // | zero region
    int* pos = (int*)alloc((size_t)N * 4);       // |
    float* gsum = (float*)alloc(64 * 128 * 4);   // |
    int* gcnt = (int*)alloc(64 * 4);             // |
    size_t zbytes = off;
    int* scantmp = (int*)alloc((size_t)N * 4);
    int* btot = (int*)alloc(1024 * 4);
    int* rowptr = (int*)alloc((size_t)(N + 1) * 4);
    int* srcs = (int*)alloc((size_t)Etot * 4);
    float* es = (float*)alloc((size_t)N * 16);
    float* ed = (float*)alloc((size_t)N * 16);
    ushort* Hb = (ushort*)alloc((size_t)N * 256 * 2);  // bf16 H
    ushort* Xb = (ushort*)alloc((size_t)N * 256 * 2);  // bf16 X (inter-layer)

    hipMemsetAsync(d_ws, 0, zbytes, stream);

    const int* srcrow = ei;
    const int* dstrow = ei + E;

    int eb = (Etot + 255) / 256;
    int nb = (N + 255) / 256;
    hist_kernel<<<eb, 256, 0, stream>>>(dstrow, cnt, Etot, E);
    scan1_kernel<<<nb, 256, 0, stream>>>(cnt, scantmp, btot, N);
    scan2_kernel<<<1, 1024, 0, stream>>>(btot, nb);
    scan3_kernel<<<nb, 256, 0, stream>>>(scantmp, btot, rowptr, N);
    fill_kernel<<<eb, 256, 0, stream>>>(srcrow, dstrow, rowptr, pos, srcs, Etot, E);

    int mT = (N + 127) / 128;
    int nodeWaveBlocks = (N + 3) / 4;

    float* out_node = (float*)d_out;                     // [N,128] f32
    float* out_graph = (float*)d_out + (size_t)N * 128;  // [64,128] f32

    // ---- layer 1: 768 -> 256 ----
    gemm_mfma<float><<<dim3(2, mT), 256, 0, stream>>>(x, W1, Hb, N, 768, 256);
    attn_wave<4><<<nodeWaveBlocks, 256, 0, stream>>>(Hb, as1, ad1, es, ed, N);
    agg_gather<4><<<nodeWaveBlocks, 256, 0, stream>>>(Hb, es, ed, rowptr, srcs, b1, g1, be1,
                                                      Xb, nullptr, N, 1);
    // ---- layer 2: 256 -> 256 ----
    gemm_mfma<ushort><<<dim3(2, mT), 256, 0, stream>>>(Xb, W2, Hb, N, 256, 256);
    attn_wave<4><<<nodeWaveBlocks, 256, 0, stream>>>(Hb, as2, ad2, es, ed, N);
    agg_gather<4><<<nodeWaveBlocks, 256, 0, stream>>>(Hb, es, ed, rowptr, srcs, b2, g2, be2,
                                                      Xb, nullptr, N, 1);
    // ---- layer 3: 256 -> 128 (no ELU; node_emb -> d_out f32) ----
    gemm_mfma<ushort><<<dim3(1, mT), 256, 0, stream>>>(Xb, W3, Hb, N, 256, 128);
    attn_wave<2><<<nodeWaveBlocks, 256, 0, stream>>>(Hb, as3, ad3, es, ed, N);
    agg_gather<2><<<nodeWaveBlocks, 256, 0, stream>>>(Hb, es, ed, rowptr, srcs, b3, g3, be3,
                                                      nullptr, out_node, N, 0);
    // ---- graph pooling ----
    gsum_kernel<<<(N + 255) / 256, 128, 0, stream>>>(out_node, batch, gsum, gcnt, N);
    gfinal_kernel<<<(64 * 128 + 255) / 256, 256, 0, stream>>>(gsum, gcnt, out_graph, 64);
}